// Round 1
// baseline (1069.020 us; speedup 1.0000x reference)
//
#include <hip/hip_runtime.h>
#include <hip/hip_bf16.h>
#include <cstdint>
#include <cstddef>

#define S_LEN 512
#define BATCH 32
#define EDIM  300
#define HDIM  128
#define NGATE 512   // 4*H
#define NCOLS 1024  // fwd 512 + bwd 512

__device__ __forceinline__ float sigm(float x) { return 1.f / (1.f + __expf(-x)); }
__device__ __forceinline__ float tanh_f(float x) { return 2.f * sigm(2.f * x) - 1.f; }

// ---------------------------------------------------------------------------
// Kernel 1: embeddings.  X[pos, e] = word emb blended with masked dep mean.
// One block per position (b*S+s); indices are block-uniform -> scalar loads.
// ---------------------------------------------------------------------------
__global__ void embed_kernel(const int* __restrict__ word_ids,
                             const int* __restrict__ deps_ids,
                             const float* __restrict__ word_table,
                             const float* __restrict__ dep_table,
                             float* __restrict__ X) {
    int pos = blockIdx.x;               // 0 .. B*S-1
    int b = pos >> 9, s = pos & (S_LEN - 1);
    int wid = word_ids[b * 3 * S_LEN + S_LEN + s];   // word_ids[b,1,s]
    const int* dp = deps_ids + (size_t)pos * 8;
    int ids[8];
    int cnt = 0;
#pragma unroll
    for (int d = 0; d < 8; ++d) {
        int id = dp[d];
        ids[d] = id;
        cnt += (id != 0 && id != 1) ? 1 : 0;
    }
    float inv = 0.5f / (float)((cnt > 0) ? cnt : 1);
    const float* wr = word_table + (size_t)wid * EDIM;
    float* xr = X + (size_t)pos * EDIM;
    for (int e = threadIdx.x; e < EDIM; e += 128) {
        float w = wr[e];
        float dsum = 0.f;
#pragma unroll
        for (int d = 0; d < 8; ++d) {
            if (ids[d] != 0 && ids[d] != 1) dsum += dep_table[ids[d] * EDIM + e];
        }
        xr[e] = (cnt > 0) ? (0.5f * w + dsum * inv) : w;
    }
}

// ---------------------------------------------------------------------------
// Kernel 2: pre-gate GEMM.  pre[m, n] = X[m,:] . W[n,:] + bias[n]
// m = b*S+s (16384), n in [0,1024): n<512 -> fwd weights, else bwd.
// Classic 128x128 tile, BK=8, 256 threads, 8x8 per thread. fp32 VALU.
// ---------------------------------------------------------------------------
__global__ __launch_bounds__(256) void gemm_pre(
        const float* __restrict__ X,
        const float* __restrict__ Wih_f, const float* __restrict__ Wih_b,
        const float* __restrict__ b_f,   const float* __restrict__ b_b,
        float* __restrict__ pre) {
    __shared__ float As[8][128];
    __shared__ float Bs[8][128];
    int tid = threadIdx.x;
    int m0 = blockIdx.x * 128;
    int n0 = blockIdx.y * 128;
    int tx = tid & 15;        // n sub-tile
    int ty = tid >> 4;        // m sub-tile
    int lr = tid >> 1;        // row loaded by this thread (0..127)
    int lk = (tid & 1) * 4;   // k offset (0 or 4)

    int nw = n0 + lr;
    const float* wrow = (nw < NGATE) ? (Wih_f + (size_t)nw * EDIM)
                                     : (Wih_b + (size_t)(nw - NGATE) * EDIM);
    const float* arow = X + (size_t)(m0 + lr) * EDIM;

    float acc[8][8];
#pragma unroll
    for (int i = 0; i < 8; ++i)
#pragma unroll
        for (int j = 0; j < 8; ++j) acc[i][j] = 0.f;

    for (int k0 = 0; k0 < EDIM; k0 += 8) {
        int kk = k0 + lk;
        float4 av, wv;
        if (kk + 3 < EDIM) {          // fully in-bounds: vector load
            av = *(const float4*)(arow + kk);
            wv = *(const float4*)(wrow + kk);
        } else {                      // tail tile (kk==300): zero, no OOB reads
            av = make_float4(0.f, 0.f, 0.f, 0.f);
            wv = make_float4(0.f, 0.f, 0.f, 0.f);
        }
        As[lk + 0][lr] = av.x; As[lk + 1][lr] = av.y;
        As[lk + 2][lr] = av.z; As[lk + 3][lr] = av.w;
        Bs[lk + 0][lr] = wv.x; Bs[lk + 1][lr] = wv.y;
        Bs[lk + 2][lr] = wv.z; Bs[lk + 3][lr] = wv.w;
        __syncthreads();
#pragma unroll
        for (int k = 0; k < 8; ++k) {
            float4 a0 = *(const float4*)&As[k][ty * 8];
            float4 a1 = *(const float4*)&As[k][ty * 8 + 4];
            float4 w0 = *(const float4*)&Bs[k][tx * 8];
            float4 w1 = *(const float4*)&Bs[k][tx * 8 + 4];
            float a[8] = {a0.x, a0.y, a0.z, a0.w, a1.x, a1.y, a1.z, a1.w};
            float w[8] = {w0.x, w0.y, w0.z, w0.w, w1.x, w1.y, w1.z, w1.w};
#pragma unroll
            for (int i = 0; i < 8; ++i)
#pragma unroll
                for (int j = 0; j < 8; ++j)
                    acc[i][j] = fmaf(a[i], w[j], acc[i][j]);
        }
        __syncthreads();
    }

    float bias[8];
#pragma unroll
    for (int j = 0; j < 8; ++j) {
        int n = n0 + tx * 8 + j;
        bias[j] = (n < NGATE) ? b_f[n] : b_b[n - NGATE];
    }
#pragma unroll
    for (int i = 0; i < 8; ++i) {
        float* op = pre + (size_t)(m0 + ty * 8 + i) * NCOLS + n0 + tx * 8;
        float4 o0 = make_float4(acc[i][0] + bias[0], acc[i][1] + bias[1],
                                acc[i][2] + bias[2], acc[i][3] + bias[3]);
        float4 o1 = make_float4(acc[i][4] + bias[4], acc[i][5] + bias[5],
                                acc[i][6] + bias[6], acc[i][7] + bias[7]);
        *(float4*)op = o0;
        *(float4*)(op + 4) = o1;
    }
}

// ---------------------------------------------------------------------------
// Kernel 3: LSTM recurrence, fused max-pool.
// One block per (batch, direction): 64 blocks x 512 threads.
// Thread t owns gate row t: Whh[t,0:128] lives in 32 float4 registers.
// h (128 floats) lives in LDS; gates round-trip through LDS each step.
// Hidden states are never written to global — running max kept in regs.
// ---------------------------------------------------------------------------
__global__ __launch_bounds__(512, 2) void lstm_rec(
        const float* __restrict__ pre,
        const float* __restrict__ Whh_f, const float* __restrict__ Whh_b,
        float* __restrict__ pooled) {
    __shared__ float h_s[HDIM];
    __shared__ float g_s[NGATE];
    int t = threadIdx.x;
    int b = blockIdx.x >> 1;
    int dir = blockIdx.x & 1;
    const float* Whh = dir ? Whh_b : Whh_f;

    float4 w[32];
    const float4* wr = (const float4*)(Whh + (size_t)t * HDIM);
#pragma unroll
    for (int j = 0; j < 32; ++j) w[j] = wr[j];

    float c = 0.f;
    float hmax = -1e30f;
    if (t < HDIM) h_s[t] = 0.f;
    __syncthreads();

    const float* prebase = pre + (size_t)b * S_LEN * NCOLS + dir * NGATE + t;
    int s = dir ? (S_LEN - 1) : 0;
    int ds = dir ? -1 : 1;
    float pre_next = prebase[(size_t)s * NCOLS];

    for (int step = 0; step < S_LEN; ++step) {
        float acc = pre_next;
        int s2 = s + ds;
        if (step < S_LEN - 1) pre_next = prebase[(long)s2 * NCOLS];

        const float4* h4 = (const float4*)h_s;
        float a0 = 0.f, a1 = 0.f, a2 = 0.f, a3 = 0.f;
#pragma unroll
        for (int j = 0; j < 32; ++j) {
            float4 hv = h4[j];
            float4 wv = w[j];
            a0 = fmaf(wv.x, hv.x, a0);
            a1 = fmaf(wv.y, hv.y, a1);
            a2 = fmaf(wv.z, hv.z, a2);
            a3 = fmaf(wv.w, hv.w, a3);
        }
        acc += (a0 + a1) + (a2 + a3);
        g_s[t] = acc;
        __syncthreads();

        if (t < HDIM) {
            float gi = g_s[t];
            float gf = g_s[t + HDIM];
            float gg = g_s[t + 2 * HDIM];
            float go = g_s[t + 3 * HDIM];
            c = sigm(gf) * c + sigm(gi) * tanh_f(gg);
            float h = sigm(go) * tanh_f(c);
            hmax = fmaxf(hmax, h);
            h_s[t] = h;
        }
        __syncthreads();
        s = s2;
    }

    if (t < HDIM) pooled[b * 256 + dir * HDIM + t] = hmax;
}

// ---------------------------------------------------------------------------
// Kernel 4: classifier.  logits[b,l] = pooled[b,:] . W_cls[l,:] + b_cls[l]
// ---------------------------------------------------------------------------
__global__ void cls_kernel(const float* __restrict__ pooled,
                           const float* __restrict__ W_cls,
                           const float* __restrict__ b_cls,
                           float* __restrict__ out) {
    int i = threadIdx.x;
    if (i < BATCH * 5) {
        int b = i / 5, l = i % 5;
        float acc = b_cls[l];
        const float* p = pooled + b * 256;
        const float* w = W_cls + l * 256;
#pragma unroll 8
        for (int j = 0; j < 256; ++j) acc = fmaf(p[j], w[j], acc);
        out[i] = acc;
    }
}

// ---------------------------------------------------------------------------
extern "C" void kernel_launch(void* const* d_in, const int* in_sizes, int n_in,
                              void* d_out, int out_size, void* d_ws, size_t ws_size,
                              hipStream_t stream) {
    const int*   word_ids   = (const int*)d_in[0];
    const int*   deps_ids   = (const int*)d_in[1];
    const float* word_table = (const float*)d_in[2];
    const float* dep_table  = (const float*)d_in[3];
    const float* Wih_f      = (const float*)d_in[4];
    const float* Whh_f      = (const float*)d_in[5];
    const float* b_f        = (const float*)d_in[6];
    const float* Wih_b      = (const float*)d_in[7];
    const float* Whh_b      = (const float*)d_in[8];
    const float* b_b        = (const float*)d_in[9];
    const float* W_cls      = (const float*)d_in[10];
    const float* b_cls      = (const float*)d_in[11];
    float* out = (float*)d_out;

    // workspace layout (fp32):
    //   X      : 16384 * 300  = 4,915,200  floats
    //   pre    : 16384 * 1024 = 16,777,216 floats
    //   pooled : 32 * 256     = 8,192      floats        total ~86.8 MB
    float* X      = (float*)d_ws;
    float* pre    = X + (size_t)BATCH * S_LEN * EDIM;
    float* pooled = pre + (size_t)BATCH * S_LEN * NCOLS;

    embed_kernel<<<BATCH * S_LEN, 128, 0, stream>>>(word_ids, deps_ids,
                                                    word_table, dep_table, X);
    gemm_pre<<<dim3(128, 8), 256, 0, stream>>>(X, Wih_f, Wih_b, b_f, b_b, pre);
    lstm_rec<<<64, 512, 0, stream>>>(pre, Whh_f, Whh_b, pooled);
    cls_kernel<<<1, 192, 0, stream>>>(pooled, W_cls, b_cls, out);
}

// Round 2
// 994.548 us; speedup vs baseline: 1.0749x; 1.0749x over previous
//
#include <hip/hip_runtime.h>
#include <hip/hip_bf16.h>
#include <cstdint>
#include <cstddef>

#define S_LEN 512
#define BATCH 32
#define EDIM  300
#define HDIM  128
#define NGATE 512   // 4*H
#define NCOLS 1024  // fwd 512 + bwd 512

__device__ __forceinline__ float sigm(float x) { return 1.f / (1.f + __expf(-x)); }
__device__ __forceinline__ float tanh_f(float x) { return 2.f * sigm(2.f * x) - 1.f; }

// DPP cross-lane move (VALU pipe — avoids the LDS pipe entirely).
// CTRL: 0xB1 = quad_perm xor1, 0x4E = quad_perm xor2, 0x124 = row_ror:4, 0x128 = row_ror:8
template <int CTRL>
__device__ __forceinline__ float dpp_mov(float x) {
    int r = __builtin_amdgcn_update_dpp(0, __float_as_int(x), CTRL, 0xF, 0xF, true);
    return __int_as_float(r);
}

// ---------------------------------------------------------------------------
// Kernel 1: embeddings.  X[pos, e] = word emb blended with masked dep mean.
// ---------------------------------------------------------------------------
__global__ void embed_kernel(const int* __restrict__ word_ids,
                             const int* __restrict__ deps_ids,
                             const float* __restrict__ word_table,
                             const float* __restrict__ dep_table,
                             float* __restrict__ X) {
    int pos = blockIdx.x;               // 0 .. B*S-1
    int b = pos >> 9, s = pos & (S_LEN - 1);
    int wid = word_ids[b * 3 * S_LEN + S_LEN + s];   // word_ids[b,1,s]
    const int* dp = deps_ids + (size_t)pos * 8;
    int ids[8];
    int cnt = 0;
#pragma unroll
    for (int d = 0; d < 8; ++d) {
        int id = dp[d];
        ids[d] = id;
        cnt += (id != 0 && id != 1) ? 1 : 0;
    }
    float inv = 0.5f / (float)((cnt > 0) ? cnt : 1);
    const float* wr = word_table + (size_t)wid * EDIM;
    float* xr = X + (size_t)pos * EDIM;
    for (int e = threadIdx.x; e < EDIM; e += 128) {
        float w = wr[e];
        float dsum = 0.f;
#pragma unroll
        for (int d = 0; d < 8; ++d) {
            if (ids[d] != 0 && ids[d] != 1) dsum += dep_table[ids[d] * EDIM + e];
        }
        xr[e] = (cnt > 0) ? (0.5f * w + dsum * inv) : w;
    }
}

// ---------------------------------------------------------------------------
// Kernel 2: pre-gate GEMM.  pre[m, n] = X[m,:] . W[n,:] + bias[n]
// ---------------------------------------------------------------------------
__global__ __launch_bounds__(256) void gemm_pre(
        const float* __restrict__ X,
        const float* __restrict__ Wih_f, const float* __restrict__ Wih_b,
        const float* __restrict__ b_f,   const float* __restrict__ b_b,
        float* __restrict__ pre) {
    __shared__ float As[8][128];
    __shared__ float Bs[8][128];
    int tid = threadIdx.x;
    int m0 = blockIdx.x * 128;
    int n0 = blockIdx.y * 128;
    int tx = tid & 15;        // n sub-tile
    int ty = tid >> 4;        // m sub-tile
    int lr = tid >> 1;        // row loaded by this thread (0..127)
    int lk = (tid & 1) * 4;   // k offset (0 or 4)

    int nw = n0 + lr;
    const float* wrow = (nw < NGATE) ? (Wih_f + (size_t)nw * EDIM)
                                     : (Wih_b + (size_t)(nw - NGATE) * EDIM);
    const float* arow = X + (size_t)(m0 + lr) * EDIM;

    float acc[8][8];
#pragma unroll
    for (int i = 0; i < 8; ++i)
#pragma unroll
        for (int j = 0; j < 8; ++j) acc[i][j] = 0.f;

    for (int k0 = 0; k0 < EDIM; k0 += 8) {
        int kk = k0 + lk;
        float4 av, wv;
        if (kk + 3 < EDIM) {
            av = *(const float4*)(arow + kk);
            wv = *(const float4*)(wrow + kk);
        } else {
            av = make_float4(0.f, 0.f, 0.f, 0.f);
            wv = make_float4(0.f, 0.f, 0.f, 0.f);
        }
        As[lk + 0][lr] = av.x; As[lk + 1][lr] = av.y;
        As[lk + 2][lr] = av.z; As[lk + 3][lr] = av.w;
        Bs[lk + 0][lr] = wv.x; Bs[lk + 1][lr] = wv.y;
        Bs[lk + 2][lr] = wv.z; Bs[lk + 3][lr] = wv.w;
        __syncthreads();
#pragma unroll
        for (int k = 0; k < 8; ++k) {
            float4 a0 = *(const float4*)&As[k][ty * 8];
            float4 a1 = *(const float4*)&As[k][ty * 8 + 4];
            float4 w0 = *(const float4*)&Bs[k][tx * 8];
            float4 w1 = *(const float4*)&Bs[k][tx * 8 + 4];
            float a[8] = {a0.x, a0.y, a0.z, a0.w, a1.x, a1.y, a1.z, a1.w};
            float w[8] = {w0.x, w0.y, w0.z, w0.w, w1.x, w1.y, w1.z, w1.w};
#pragma unroll
            for (int i = 0; i < 8; ++i)
#pragma unroll
                for (int j = 0; j < 8; ++j)
                    acc[i][j] = fmaf(a[i], w[j], acc[i][j]);
        }
        __syncthreads();
    }

    float bias[8];
#pragma unroll
    for (int j = 0; j < 8; ++j) {
        int n = n0 + tx * 8 + j;
        bias[j] = (n < NGATE) ? b_f[n] : b_b[n - NGATE];
    }
#pragma unroll
    for (int i = 0; i < 8; ++i) {
        float* op = pre + (size_t)(m0 + ty * 8 + i) * NCOLS + n0 + tx * 8;
        float4 o0 = make_float4(acc[i][0] + bias[0], acc[i][1] + bias[1],
                                acc[i][2] + bias[2], acc[i][3] + bias[3]);
        float4 o1 = make_float4(acc[i][4] + bias[4], acc[i][5] + bias[5],
                                acc[i][6] + bias[6], acc[i][7] + bias[7]);
        *(float4*)op = o0;
        *(float4*)(op + 4) = o1;
    }
}

// ---------------------------------------------------------------------------
// Kernel 3: LSTM recurrence, fused max-pool.  Split-K + DPP butterfly.
// One block per (batch, direction): 64 blocks x 512 threads.
// Lane (row=l>>4, kpos=l&15) of wave w computes, for 16 gates
// [gbase, gbase+16) where gbase = w*64 + row*16, partial dots over its
// private k-slice [8*kpos, 8*kpos+8).  h read from LDS: only 2 b128/wave.
// Reduction across the 16 kpos lanes is done in-register on the VALU pipe:
//   stage xor1/xor2 (quad_perm, j-splitting) then row_ror:4/:8.
// Lane p ends with the complete dot for gate gbase+p  (== threadIdx.x).
// ---------------------------------------------------------------------------
__global__ __launch_bounds__(512, 2) void lstm_rec(
        const float* __restrict__ pre,
        const float* __restrict__ Whh_f, const float* __restrict__ Whh_b,
        float* __restrict__ pooled) {
    __shared__ float h_s[HDIM];
    __shared__ float g_s[NGATE];
    int t = threadIdx.x;
    int lane = t & 63;
    int wv_id = t >> 6;
    int row = lane >> 4;
    int kpos = lane & 15;
    int gbase = wv_id * 64 + row * 16;
    int b = blockIdx.x >> 1;
    int dir = blockIdx.x & 1;
    const float* Whh = dir ? Whh_b : Whh_f;

    // weights: w[j][i] = Whh[gbase+j][kpos*8+i]   (128 VGPRs)
    float4 wA[16], wB[16];
#pragma unroll
    for (int j = 0; j < 16; ++j) {
        const float* rowp = Whh + (size_t)(gbase + j) * HDIM + kpos * 8;
        wA[j] = *(const float4*)rowp;
        wB[j] = *(const float4*)(rowp + 4);
    }

    float c = 0.f;
    float hmax = -1e30f;
    if (t < HDIM) h_s[t] = 0.f;
    __syncthreads();

    const float* prebase = pre + (size_t)b * S_LEN * NCOLS + dir * NGATE + t;
    int s = dir ? (S_LEN - 1) : 0;
    int ds = dir ? -1 : 1;
    float pre_n1 = prebase[(long)s * NCOLS];
    float pre_n2 = prebase[(long)(s + ds) * NCOLS];

    for (int step = 0; step < S_LEN; ++step) {
        float cur = pre_n1;
        pre_n1 = pre_n2;
        if (step + 2 < S_LEN) pre_n2 = prebase[(long)(s + 2 * ds) * NCOLS];

        // h slice for this lane's k-range: 8 floats, 2 x b128
        const float4* h4 = (const float4*)(h_s + kpos * 8);
        float4 h0 = h4[0], h1 = h4[1];

        // 16 partial dots (independent 8-deep FMA chains -> good ILP)
        float P[16];
#pragma unroll
        for (int j = 0; j < 16; ++j) {
            float a = fmaf(wA[j].x, h0.x, wA[j].y * h0.y);
            float bb = fmaf(wA[j].z, h0.z, wA[j].w * h0.w);
            float cc = fmaf(wB[j].x, h1.x, wB[j].y * h1.y);
            float dd = fmaf(wB[j].z, h1.z, wB[j].w * h1.w);
            P[j] = (a + bb) + (cc + dd);
        }

        // stage 1: xor1 (quad_perm), keep j with j&1 == kpos&1
        bool par1 = (kpos & 1) != 0;
        float Q[8];
#pragma unroll
        for (int i = 0; i < 8; ++i) {
            float send = par1 ? P[2 * i] : P[2 * i + 1];
            float keep = par1 ? P[2 * i + 1] : P[2 * i];
            Q[i] = keep + dpp_mov<0xB1>(send);
        }
        // stage 2: xor2, keep j with (j>>1)&1 == (kpos>>1)&1
        bool par2 = (kpos & 2) != 0;
        float R[4];
#pragma unroll
        for (int i = 0; i < 4; ++i) {
            float send = par2 ? Q[2 * i] : Q[2 * i + 1];
            float keep = par2 ? Q[2 * i + 1] : Q[2 * i];
            R[i] = keep + dpp_mov<0x4E>(send);
        }
        // stages 3-4: rotate-reduce across the 4 quads (no j-split)
#pragma unroll
        for (int i = 0; i < 4; ++i) {
            R[i] += dpp_mov<0x124>(R[i]);
            R[i] += dpp_mov<0x128>(R[i]);
        }
        // lane kpos holds gate 4i+(kpos&3) in R[i]; output gate = kpos -> R[kpos>>2]
        float r01 = (kpos & 4) ? R[1] : R[0];
        float r23 = (kpos & 4) ? R[3] : R[2];
        float dot = (kpos & 8) ? r23 : r01;

        g_s[t] = cur + dot;
        __syncthreads();

        if (t < HDIM) {
            float gi = g_s[t];
            float gf = g_s[t + HDIM];
            float gg = g_s[t + 2 * HDIM];
            float go = g_s[t + 3 * HDIM];
            c = sigm(gf) * c + sigm(gi) * tanh_f(gg);
            float h = sigm(go) * tanh_f(c);
            hmax = fmaxf(hmax, h);
            h_s[t] = h;
        }
        __syncthreads();
        s += ds;
    }

    if (t < HDIM) pooled[b * 256 + dir * HDIM + t] = hmax;
}

// ---------------------------------------------------------------------------
// Kernel 4: classifier.
// ---------------------------------------------------------------------------
__global__ void cls_kernel(const float* __restrict__ pooled,
                           const float* __restrict__ W_cls,
                           const float* __restrict__ b_cls,
                           float* __restrict__ out) {
    int i = threadIdx.x;
    if (i < BATCH * 5) {
        int b = i / 5, l = i % 5;
        float acc = b_cls[l];
        const float* p = pooled + b * 256;
        const float* w = W_cls + l * 256;
#pragma unroll 8
        for (int j = 0; j < 256; ++j) acc = fmaf(p[j], w[j], acc);
        out[i] = acc;
    }
}

// ---------------------------------------------------------------------------
extern "C" void kernel_launch(void* const* d_in, const int* in_sizes, int n_in,
                              void* d_out, int out_size, void* d_ws, size_t ws_size,
                              hipStream_t stream) {
    const int*   word_ids   = (const int*)d_in[0];
    const int*   deps_ids   = (const int*)d_in[1];
    const float* word_table = (const float*)d_in[2];
    const float* dep_table  = (const float*)d_in[3];
    const float* Wih_f      = (const float*)d_in[4];
    const float* Whh_f      = (const float*)d_in[5];
    const float* b_f        = (const float*)d_in[6];
    const float* Wih_b      = (const float*)d_in[7];
    const float* Whh_b      = (const float*)d_in[8];
    const float* b_b        = (const float*)d_in[9];
    const float* W_cls      = (const float*)d_in[10];
    const float* b_cls      = (const float*)d_in[11];
    float* out = (float*)d_out;

    float* X      = (float*)d_ws;
    float* pre    = X + (size_t)BATCH * S_LEN * EDIM;
    float* pooled = pre + (size_t)BATCH * S_LEN * NCOLS;

    embed_kernel<<<BATCH * S_LEN, 128, 0, stream>>>(word_ids, deps_ids,
                                                    word_table, dep_table, X);
    gemm_pre<<<dim3(128, 8), 256, 0, stream>>>(X, Wih_f, Wih_b, b_f, b_b, pre);
    lstm_rec<<<64, 512, 0, stream>>>(pre, Whh_f, Whh_b, pooled);
    cls_kernel<<<1, 192, 0, stream>>>(pooled, W_cls, b_cls, out);
}

// Round 4
// 751.372 us; speedup vs baseline: 1.4228x; 1.3236x over previous
//
#include <hip/hip_runtime.h>
#include <hip/hip_bf16.h>
#include <cstdint>
#include <cstddef>

#define S_LEN 512
#define BATCH 32
#define EDIM  300
#define HDIM  128
#define NGATE 512   // 4*H
#define NCOLS 1024  // fwd 512 + bwd 512

typedef float f2 __attribute__((ext_vector_type(2)));

__device__ __forceinline__ float sigm_fast(float x) {
    // 1/(1+exp(-x)) with v_rcp (approx, ~1ulp — fine vs 8e-4 threshold)
    return __builtin_amdgcn_rcpf(1.f + __expf(-x));
}
__device__ __forceinline__ float tanh_fast(float x) {
    return 2.f * sigm_fast(2.f * x) - 1.f;
}

// DPP cross-lane move (VALU pipe). 0xB1 = quad_perm xor1, 0x4E = quad_perm
// xor2, 0x124 = row_ror:4, 0x128 = row_ror:8.  (verified in R1: absmax 0.0)
template <int CTRL>
__device__ __forceinline__ float dpp_mov(float x) {
    int r = __builtin_amdgcn_update_dpp(0, __float_as_int(x), CTRL, 0xF, 0xF, true);
    return __int_as_float(r);
}
// ds_swizzle with compile-time pattern (BitMode: xor_mask<<10 | and 0x1F)
template <int IMM>
__device__ __forceinline__ float swz(float x) {
    return __int_as_float(__builtin_amdgcn_ds_swizzle(__float_as_int(x), IMM));
}

// ---------------------------------------------------------------------------
// Kernel 1: embeddings (unchanged — ~10 µs)
// ---------------------------------------------------------------------------
__global__ void embed_kernel(const int* __restrict__ word_ids,
                             const int* __restrict__ deps_ids,
                             const float* __restrict__ word_table,
                             const float* __restrict__ dep_table,
                             float* __restrict__ X) {
    int pos = blockIdx.x;
    int b = pos >> 9, s = pos & (S_LEN - 1);
    int wid = word_ids[b * 3 * S_LEN + S_LEN + s];
    const int* dp = deps_ids + (size_t)pos * 8;
    int ids[8];
    int cnt = 0;
#pragma unroll
    for (int d = 0; d < 8; ++d) {
        int id = dp[d];
        ids[d] = id;
        cnt += (id != 0 && id != 1) ? 1 : 0;
    }
    float inv = 0.5f / (float)((cnt > 0) ? cnt : 1);
    const float* wr = word_table + (size_t)wid * EDIM;
    float* xr = X + (size_t)pos * EDIM;
    for (int e = threadIdx.x; e < EDIM; e += 128) {
        float w = wr[e];
        float dsum = 0.f;
#pragma unroll
        for (int d = 0; d < 8; ++d) {
            if (ids[d] != 0 && ids[d] != 1) dsum += dep_table[ids[d] * EDIM + e];
        }
        xr[e] = (cnt > 0) ? (0.5f * w + dsum * inv) : w;
    }
}

// ---------------------------------------------------------------------------
// Kernel 2: pre-gate GEMM (unchanged this round)
// ---------------------------------------------------------------------------
__global__ __launch_bounds__(256) void gemm_pre(
        const float* __restrict__ X,
        const float* __restrict__ Wih_f, const float* __restrict__ Wih_b,
        const float* __restrict__ b_f,   const float* __restrict__ b_b,
        float* __restrict__ pre) {
    __shared__ float As[8][128];
    __shared__ float Bs[8][128];
    int tid = threadIdx.x;
    int m0 = blockIdx.x * 128;
    int n0 = blockIdx.y * 128;
    int tx = tid & 15;
    int ty = tid >> 4;
    int lr = tid >> 1;
    int lk = (tid & 1) * 4;

    int nw = n0 + lr;
    const float* wrow = (nw < NGATE) ? (Wih_f + (size_t)nw * EDIM)
                                     : (Wih_b + (size_t)(nw - NGATE) * EDIM);
    const float* arow = X + (size_t)(m0 + lr) * EDIM;

    float acc[8][8];
#pragma unroll
    for (int i = 0; i < 8; ++i)
#pragma unroll
        for (int j = 0; j < 8; ++j) acc[i][j] = 0.f;

    for (int k0 = 0; k0 < EDIM; k0 += 8) {
        int kk = k0 + lk;
        float4 av, wv;
        if (kk + 3 < EDIM) {
            av = *(const float4*)(arow + kk);
            wv = *(const float4*)(wrow + kk);
        } else {
            av = make_float4(0.f, 0.f, 0.f, 0.f);
            wv = make_float4(0.f, 0.f, 0.f, 0.f);
        }
        As[lk + 0][lr] = av.x; As[lk + 1][lr] = av.y;
        As[lk + 2][lr] = av.z; As[lk + 3][lr] = av.w;
        Bs[lk + 0][lr] = wv.x; Bs[lk + 1][lr] = wv.y;
        Bs[lk + 2][lr] = wv.z; Bs[lk + 3][lr] = wv.w;
        __syncthreads();
#pragma unroll
        for (int k = 0; k < 8; ++k) {
            float4 a0 = *(const float4*)&As[k][ty * 8];
            float4 a1 = *(const float4*)&As[k][ty * 8 + 4];
            float4 w0 = *(const float4*)&Bs[k][tx * 8];
            float4 w1 = *(const float4*)&Bs[k][tx * 8 + 4];
            float a[8] = {a0.x, a0.y, a0.z, a0.w, a1.x, a1.y, a1.z, a1.w};
            float w[8] = {w0.x, w0.y, w0.z, w0.w, w1.x, w1.y, w1.z, w1.w};
#pragma unroll
            for (int i = 0; i < 8; ++i)
#pragma unroll
                for (int j = 0; j < 8; ++j)
                    acc[i][j] = fmaf(a[i], w[j], acc[i][j]);
        }
        __syncthreads();
    }

    float bias[8];
#pragma unroll
    for (int j = 0; j < 8; ++j) {
        int n = n0 + tx * 8 + j;
        bias[j] = (n < NGATE) ? b_f[n] : b_b[n - NGATE];
    }
#pragma unroll
    for (int i = 0; i < 8; ++i) {
        float* op = pre + (size_t)(m0 + ty * 8 + i) * NCOLS + n0 + tx * 8;
        float4 o0 = make_float4(acc[i][0] + bias[0], acc[i][1] + bias[1],
                                acc[i][2] + bias[2], acc[i][3] + bias[3]);
        float4 o1 = make_float4(acc[i][4] + bias[4], acc[i][5] + bias[5],
                                acc[i][6] + bias[6], acc[i][7] + bias[7]);
        *(float4*)op = o0;
        *(float4*)(op + 4) = o1;
    }
}

// ---------------------------------------------------------------------------
// Kernel 3: LSTM recurrence v3.  One raw barrier/step, distributed activation.
//
// 64 blocks (b,dir) x 512 threads.  Wave w owns h-indices [16w, 16w+16).
// Lane l: kpos = l&15 (k-slice [8*kpos, 8*kpos+8)), rgrp = l>>4.
// j in [0,16) -> gate row  (j>>2)*128 + 16w + 4*rgrp + (j&3).
// After the verified DPP butterfly, lane kpos holds gate j==kpos:
//   gt = kpos>>2, hidx = 16w + 4*rgrp + (kpos&3).
// XOR-swizzles 4/8/12 gather the other 3 gate types for the SAME hidx
// (xor on bits 2-3 flips gt only).  Every lane computes c/h (4x redundant),
// lanes gt==0 write h to LDS.  Raw s_barrier with lgkmcnt-only drain keeps
// the 2-step-ahead global prefetch of `pre` in flight across steps.
// ---------------------------------------------------------------------------
__global__ __launch_bounds__(512, 2) void lstm_rec(
        const float* __restrict__ pre,
        const float* __restrict__ Whh_f, const float* __restrict__ Whh_b,
        float* __restrict__ pooled) {
    __shared__ float h_s[HDIM];
    int t = threadIdx.x;
    int lane = t & 63;
    int wv_id = t >> 6;
    int kpos = lane & 15;
    int rgrp = lane >> 4;
    int gt = kpos >> 2;
    int hidx = wv_id * 16 + rgrp * 4 + (kpos & 3);
    int b = blockIdx.x >> 1;
    int dir = blockIdx.x & 1;
    const float* Whh = dir ? Whh_b : Whh_f;

    // weights: w2[j][q] covers Whh[row(j)][kpos*8 + 2q .. +2q+1]
    f2 w2[16][4];
#pragma unroll
    for (int j = 0; j < 16; ++j) {
        int row = (j >> 2) * HDIM + wv_id * 16 + rgrp * 4 + (j & 3);
        const f2* rp = (const f2*)(Whh + (size_t)row * HDIM + kpos * 8);
        w2[j][0] = rp[0]; w2[j][1] = rp[1]; w2[j][2] = rp[2]; w2[j][3] = rp[3];
    }

    float c = 0.f;
    float hmax = -1e30f;
    if (t < HDIM) h_s[t] = 0.f;

    int coloff = dir * NGATE + gt * HDIM + hidx;
    const float* prebase = pre + (size_t)b * S_LEN * NCOLS + coloff;
    int s = dir ? (S_LEN - 1) : 0;
    int ds = dir ? -1 : 1;
    float pre_n1 = prebase[(long)s * NCOLS];
    float pre_n2 = prebase[(long)(s + ds) * NCOLS];

    asm volatile("s_waitcnt lgkmcnt(0)\n\ts_barrier" ::: "memory");

    for (int step = 0; step < S_LEN; ++step) {
        float cur = pre_n1;
        pre_n1 = pre_n2;
        if (step + 2 < S_LEN) pre_n2 = prebase[(long)(s + 2 * ds) * NCOLS];

        // h slice for this lane's k-range: 8 floats, 2 x ds_read_b128
        union { float4 v4; f2 v2[2]; } u0, u1;
        const float4* h4 = (const float4*)(h_s + kpos * 8);
        u0.v4 = h4[0];
        u1.v4 = h4[1];

        // 16 partial dots, packed fp32 (v_pk_fma_f32)
        float P[16];
#pragma unroll
        for (int j = 0; j < 16; ++j) {
            f2 acc = w2[j][0] * u0.v2[0];
            acc += w2[j][1] * u0.v2[1];
            acc += w2[j][2] * u1.v2[0];
            acc += w2[j][3] * u1.v2[1];
            P[j] = acc.x + acc.y;
        }

        // verified butterfly: reduce P[16] across the 16 kpos lanes.
        bool par1 = (kpos & 1) != 0;
        float Q[8];
#pragma unroll
        for (int i = 0; i < 8; ++i) {
            float send = par1 ? P[2 * i] : P[2 * i + 1];
            float keep = par1 ? P[2 * i + 1] : P[2 * i];
            Q[i] = keep + dpp_mov<0xB1>(send);
        }
        bool par2 = (kpos & 2) != 0;
        float R[4];
#pragma unroll
        for (int i = 0; i < 4; ++i) {
            float send = par2 ? Q[2 * i] : Q[2 * i + 1];
            float keep = par2 ? Q[2 * i + 1] : Q[2 * i];
            R[i] = keep + dpp_mov<0x4E>(send);
        }
#pragma unroll
        for (int i = 0; i < 4; ++i) {
            R[i] += dpp_mov<0x124>(R[i]);
            R[i] += dpp_mov<0x128>(R[i]);
        }
        float r01 = (kpos & 4) ? R[1] : R[0];
        float r23 = (kpos & 4) ? R[3] : R[2];
        float dot = (kpos & 8) ? r23 : r01;

        // lane now holds gate (gt, hidx); add pre-gate value
        float g0 = cur + dot;

        // gather the other 3 gate types for this hidx (xor flips gt only)
        float g1 = swz<0x101F>(g0);   // xor 4  -> gt^1
        float g2 = swz<0x201F>(g0);   // xor 8  -> gt^2
        float g3 = swz<0x301F>(g0);   // xor 12 -> gt^3
        // s_m = g[m ^ gt] has gate type m
        bool t0 = (gt & 1) != 0;
        bool t1 = (gt & 2) != 0;
        float b0 = t0 ? g1 : g0;
        float b1 = t0 ? g0 : g1;
        float b2 = t0 ? g3 : g2;
        float b3 = t0 ? g2 : g3;
        float gi = t1 ? b2 : b0;
        float gf = t1 ? b3 : b1;
        float gg = t1 ? b0 : b2;
        float go = t1 ? b1 : b3;

        c = sigm_fast(gf) * c + sigm_fast(gi) * tanh_fast(gg);
        float h = sigm_fast(go) * tanh_fast(c);
        hmax = fmaxf(hmax, h);

        if (gt == 0) h_s[wv_id * 16 + rgrp * 4 + kpos] = h;
        asm volatile("s_waitcnt lgkmcnt(0)\n\ts_barrier" ::: "memory");
        s += ds;
    }

    if (gt == 0) pooled[b * 256 + dir * HDIM + hidx] = hmax;
}

// ---------------------------------------------------------------------------
// Kernel 4: classifier (unchanged)
// ---------------------------------------------------------------------------
__global__ void cls_kernel(const float* __restrict__ pooled,
                           const float* __restrict__ W_cls,
                           const float* __restrict__ b_cls,
                           float* __restrict__ out) {
    int i = threadIdx.x;
    if (i < BATCH * 5) {
        int b = i / 5, l = i % 5;
        float acc = b_cls[l];
        const float* p = pooled + b * 256;
        const float* w = W_cls + l * 256;
#pragma unroll 8
        for (int j = 0; j < 256; ++j) acc = fmaf(p[j], w[j], acc);
        out[i] = acc;
    }
}

// ---------------------------------------------------------------------------
extern "C" void kernel_launch(void* const* d_in, const int* in_sizes, int n_in,
                              void* d_out, int out_size, void* d_ws, size_t ws_size,
                              hipStream_t stream) {
    const int*   word_ids   = (const int*)d_in[0];
    const int*   deps_ids   = (const int*)d_in[1];
    const float* word_table = (const float*)d_in[2];
    const float* dep_table  = (const float*)d_in[3];
    const float* Wih_f      = (const float*)d_in[4];
    const float* Whh_f      = (const float*)d_in[5];
    const float* b_f        = (const float*)d_in[6];
    const float* Wih_b      = (const float*)d_in[7];
    const float* Whh_b      = (const float*)d_in[8];
    const float* b_b        = (const float*)d_in[9];
    const float* W_cls      = (const float*)d_in[10];
    const float* b_cls      = (const float*)d_in[11];
    float* out = (float*)d_out;

    float* X      = (float*)d_ws;
    float* pre    = X + (size_t)BATCH * S_LEN * EDIM;
    float* pooled = pre + (size_t)BATCH * S_LEN * NCOLS;

    embed_kernel<<<BATCH * S_LEN, 128, 0, stream>>>(word_ids, deps_ids,
                                                    word_table, dep_table, X);
    gemm_pre<<<dim3(128, 8), 256, 0, stream>>>(X, Wih_f, Wih_b, b_f, b_b, pre);
    lstm_rec<<<64, 512, 0, stream>>>(pre, Whh_f, Whh_b, pooled);
    cls_kernel<<<1, 192, 0, stream>>>(pooled, W_cls, b_cls, out);
}

// Round 5
// 665.377 us; speedup vs baseline: 1.6066x; 1.1292x over previous
//
#include <hip/hip_runtime.h>
#include <hip/hip_bf16.h>
#include <cstdint>
#include <cstddef>

#define S_LEN 512
#define BATCH 32
#define EDIM  300
#define KPAD  320
#define K3    960   // [Xh|Xh|Xl] / [Wh|Wl|Wh]
#define HDIM  128
#define NGATE 512   // 4*H
#define NCOLS 1024  // fwd 512 + bwd 512

typedef float  f2 __attribute__((ext_vector_type(2)));
typedef float  f4v __attribute__((ext_vector_type(4)));
typedef short  short8 __attribute__((ext_vector_type(8)));

__device__ __forceinline__ float sigm_fast(float x) {
    return __builtin_amdgcn_rcpf(1.f + __expf(-x));
}
__device__ __forceinline__ float tanh_fast(float x) {
    return 2.f * sigm_fast(2.f * x) - 1.f;
}

// DPP cross-lane move (VALU pipe). quad_perm: 0xB1=xor1, 0x4E=xor2, 0x1B=xor3;
// row_ror: 0x124=ror:4, 0x128=ror:8.  (butterfly pieces verified R1/R4)
template <int CTRL>
__device__ __forceinline__ float dpp_mov(float x) {
    int r = __builtin_amdgcn_update_dpp(0, __float_as_int(x), CTRL, 0xF, 0xF, true);
    return __int_as_float(r);
}

__device__ __forceinline__ void bf16_split(float v, ushort& hi, ushort& lo) {
    __hip_bfloat16 hb = __float2bfloat16(v);
    float hf = __bfloat162float(hb);
    __hip_bfloat16 lb = __float2bfloat16(v - hf);
    hi = *reinterpret_cast<ushort*>(&hb);
    lo = *reinterpret_cast<ushort*>(&lb);
}

// ---------------------------------------------------------------------------
// Kernel 1: embeddings -> Xcat (bf16 hi/lo split), row = [Xh | Xh | Xl], K3=960
// ---------------------------------------------------------------------------
__global__ void embed_xcat(const int* __restrict__ word_ids,
                           const int* __restrict__ deps_ids,
                           const float* __restrict__ word_table,
                           const float* __restrict__ dep_table,
                           ushort* __restrict__ Xcat) {
    int pos = blockIdx.x;
    int b = pos >> 9, s = pos & (S_LEN - 1);
    int wid = word_ids[b * 3 * S_LEN + S_LEN + s];
    const int* dp = deps_ids + (size_t)pos * 8;
    int ids[8];
    int cnt = 0;
#pragma unroll
    for (int d = 0; d < 8; ++d) {
        int id = dp[d];
        ids[d] = id;
        cnt += (id != 0 && id != 1) ? 1 : 0;
    }
    float inv = 0.5f / (float)((cnt > 0) ? cnt : 1);
    const float* wr = word_table + (size_t)wid * EDIM;
    ushort* xr = Xcat + (size_t)pos * K3;
    for (int e = threadIdx.x; e < KPAD; e += 128) {
        float v = 0.f;
        if (e < EDIM) {
            float w = wr[e];
            float dsum = 0.f;
#pragma unroll
            for (int d = 0; d < 8; ++d) {
                if (ids[d] != 0 && ids[d] != 1) dsum += dep_table[ids[d] * EDIM + e];
            }
            v = (cnt > 0) ? (0.5f * w + dsum * inv) : w;
        }
        ushort hu, lu;
        bf16_split(v, hu, lu);
        xr[e] = hu;
        xr[KPAD + e] = hu;
        xr[2 * KPAD + e] = lu;
    }
}

// ---------------------------------------------------------------------------
// Kernel 1b: Wih -> Wcat, row n (0..1023, fwd then bwd) = [Wh | Wl | Wh]
// ---------------------------------------------------------------------------
__global__ void wcat_kernel(const float* __restrict__ Wih_f,
                            const float* __restrict__ Wih_b,
                            ushort* __restrict__ Wcat) {
    int n = blockIdx.x;
    const float* src = (n < NGATE) ? (Wih_f + (size_t)n * EDIM)
                                   : (Wih_b + (size_t)(n - NGATE) * EDIM);
    ushort* wr = Wcat + (size_t)n * K3;
    for (int e = threadIdx.x; e < KPAD; e += 128) {
        float v = (e < EDIM) ? src[e] : 0.f;
        ushort hu, lu;
        bf16_split(v, hu, lu);
        wr[e] = hu;
        wr[KPAD + e] = lu;
        wr[2 * KPAD + e] = hu;
    }
}

// ---------------------------------------------------------------------------
// Kernel 2: MFMA GEMM.  pre[m,n] = Xcat[m,:].Wcat[n,:] + bias[n]  (bf16x3)
// 128x128 tile, BK=32, 256 threads (4 waves, 2x2 wave grid of 64x64).
// A-frag layout [m=lane&15][k=quad*8+j]; C/D col=lane&15, row=quad*4+reg.
// ---------------------------------------------------------------------------
__global__ __launch_bounds__(256) void gemm_mfma(
        const ushort* __restrict__ Xcat,
        const ushort* __restrict__ Wcat,
        const float* __restrict__ b_f, const float* __restrict__ b_b,
        float* __restrict__ pre) {
    __shared__ ushort Asub[128 * 32];
    __shared__ ushort Bsub[128 * 32];
    int tid = threadIdx.x;
    int wave = tid >> 6, lane = tid & 63;
    int lid = lane & 15, quad = lane >> 4;
    int m0 = blockIdx.x * 128, n0 = blockIdx.y * 128;
    int wm = (wave >> 1) * 64, wn = (wave & 1) * 64;

    f4v acc[4][4];
#pragma unroll
    for (int i = 0; i < 4; ++i)
#pragma unroll
        for (int j = 0; j < 4; ++j) acc[i][j] = (f4v)0.f;

    float bias[4];
#pragma unroll
    for (int nt = 0; nt < 4; ++nt) {
        int n = n0 + wn + nt * 16 + lid;
        bias[nt] = (n < NGATE) ? b_f[n] : b_b[n - NGATE];
    }

    // staging: chunk c (16 B) = tile row c>>2, k-chunk c&3.  thread loads c=tid, tid+256
    int c0 = tid, c1 = tid + 256;
    const ushort* aptr0 = Xcat + (size_t)(m0 + (c0 >> 2)) * K3 + (c0 & 3) * 8;
    const ushort* aptr1 = Xcat + (size_t)(m0 + (c1 >> 2)) * K3 + (c1 & 3) * 8;
    const ushort* bptr0 = Wcat + (size_t)(n0 + (c0 >> 2)) * K3 + (c0 & 3) * 8;
    const ushort* bptr1 = Wcat + (size_t)(n0 + (c1 >> 2)) * K3 + (c1 & 3) * 8;

    short8 ra0 = *(const short8*)(aptr0);
    short8 ra1 = *(const short8*)(aptr1);
    short8 rb0 = *(const short8*)(bptr0);
    short8 rb1 = *(const short8*)(bptr1);

    for (int k0 = 0; k0 < K3; k0 += 32) {
        __syncthreads();                       // prev iter's LDS reads done
        *(short8*)&Asub[c0 * 8] = ra0;
        *(short8*)&Asub[c1 * 8] = ra1;
        *(short8*)&Bsub[c0 * 8] = rb0;
        *(short8*)&Bsub[c1 * 8] = rb1;
        __syncthreads();
        if (k0 + 32 < K3) {                    // prefetch next tile (overlaps MFMA)
            ra0 = *(const short8*)(aptr0 + k0 + 32);
            ra1 = *(const short8*)(aptr1 + k0 + 32);
            rb0 = *(const short8*)(bptr0 + k0 + 32);
            rb1 = *(const short8*)(bptr1 + k0 + 32);
        }
        short8 aF[4], bF[4];
#pragma unroll
        for (int mt = 0; mt < 4; ++mt)
            aF[mt] = *(const short8*)&Asub[(wm + mt * 16 + lid) * 32 + quad * 8];
#pragma unroll
        for (int nt = 0; nt < 4; ++nt)
            bF[nt] = *(const short8*)&Bsub[(wn + nt * 16 + lid) * 32 + quad * 8];
#pragma unroll
        for (int mt = 0; mt < 4; ++mt)
#pragma unroll
            for (int nt = 0; nt < 4; ++nt)
                acc[mt][nt] = __builtin_amdgcn_mfma_f32_16x16x32_bf16(
                    aF[mt], bF[nt], acc[mt][nt], 0, 0, 0);
    }

#pragma unroll
    for (int mt = 0; mt < 4; ++mt)
#pragma unroll
        for (int nt = 0; nt < 4; ++nt) {
            int n = n0 + wn + nt * 16 + lid;
#pragma unroll
            for (int r = 0; r < 4; ++r) {
                int m = m0 + wm + mt * 16 + quad * 4 + r;
                pre[(size_t)m * NCOLS + n] = acc[mt][nt][r] + bias[nt];
            }
        }
}

// ---------------------------------------------------------------------------
// Kernel 3: LSTM recurrence v4.  Types-in-quad remap: gate gather is 3
// quad_perm DPPs (VALU) instead of 3 ds_swizzle LDS round-trips.
// Lane l: kpos=l&15, rgrp=l>>4; j -> gate row (j&3)*128 + 16w+4rgrp+(j>>2).
// Butterfly (verified) leaves lane kpos holding gate j==kpos:
//   type tau = kpos&3, hidx = 16w + 4*rgrp + (kpos>>2)  -- quad-mates hold
//   the other 3 types of the SAME hidx -> quad_perm xor1/xor2/xor3.
// ---------------------------------------------------------------------------
__global__ __launch_bounds__(512, 2) void lstm_rec(
        const float* __restrict__ pre,
        const float* __restrict__ Whh_f, const float* __restrict__ Whh_b,
        float* __restrict__ pooled) {
    __shared__ float h_s[HDIM];
    int t = threadIdx.x;
    int lane = t & 63;
    int wv_id = t >> 6;
    int kpos = lane & 15;
    int rgrp = lane >> 4;
    int hidx = wv_id * 16 + rgrp * 4 + (kpos >> 2);
    int b = blockIdx.x >> 1;
    int dir = blockIdx.x & 1;
    const float* Whh = dir ? Whh_b : Whh_f;

    // weights: w2[j][q] covers Whh[row(j)][kpos*8 + 2q .. +2q+1]
    f2 w2[16][4];
#pragma unroll
    for (int j = 0; j < 16; ++j) {
        int row = (j & 3) * HDIM + wv_id * 16 + rgrp * 4 + (j >> 2);
        const f2* rp = (const f2*)(Whh + (size_t)row * HDIM + kpos * 8);
        w2[j][0] = rp[0]; w2[j][1] = rp[1]; w2[j][2] = rp[2]; w2[j][3] = rp[3];
    }

    float c = 0.f;
    float hmax = -1e30f;
    if (t < HDIM) h_s[t] = 0.f;

    int coloff = dir * NGATE + (kpos & 3) * HDIM + hidx;
    const float* prebase = pre + (size_t)b * S_LEN * NCOLS + coloff;
    int s = dir ? (S_LEN - 1) : 0;
    int ds = dir ? -1 : 1;
    float pre_n1 = prebase[(long)s * NCOLS];
    float pre_n2 = prebase[(long)(s + ds) * NCOLS];

    asm volatile("s_waitcnt lgkmcnt(0)\n\ts_barrier" ::: "memory");

    for (int step = 0; step < S_LEN; ++step) {
        float cur = pre_n1;
        pre_n1 = pre_n2;
        if (step + 2 < S_LEN) pre_n2 = prebase[(long)(s + 2 * ds) * NCOLS];

        union { float4 v4; f2 v2[2]; } u0, u1;
        const float4* h4 = (const float4*)(h_s + kpos * 8);
        u0.v4 = h4[0];
        u1.v4 = h4[1];

        float P[16];
#pragma unroll
        for (int j = 0; j < 16; ++j) {
            f2 acc = w2[j][0] * u0.v2[0];
            acc += w2[j][1] * u0.v2[1];
            acc += w2[j][2] * u1.v2[0];
            acc += w2[j][3] * u1.v2[1];
            P[j] = acc.x + acc.y;
        }

        // verified butterfly: lane kpos ends with full dot of gate j==kpos
        bool par1 = (kpos & 1) != 0;
        float Q[8];
#pragma unroll
        for (int i = 0; i < 8; ++i) {
            float send = par1 ? P[2 * i] : P[2 * i + 1];
            float keep = par1 ? P[2 * i + 1] : P[2 * i];
            Q[i] = keep + dpp_mov<0xB1>(send);
        }
        bool par2 = (kpos & 2) != 0;
        float R[4];
#pragma unroll
        for (int i = 0; i < 4; ++i) {
            float send = par2 ? Q[2 * i] : Q[2 * i + 1];
            float keep = par2 ? Q[2 * i + 1] : Q[2 * i];
            R[i] = keep + dpp_mov<0x4E>(send);
        }
#pragma unroll
        for (int i = 0; i < 4; ++i) {
            R[i] += dpp_mov<0x124>(R[i]);
            R[i] += dpp_mov<0x128>(R[i]);
        }
        float r01 = (kpos & 4) ? R[1] : R[0];
        float r23 = (kpos & 4) ? R[3] : R[2];
        float dot = (kpos & 8) ? r23 : r01;

        float g0 = cur + dot;                 // gate (tau = kpos&3, hidx)

        // gather other 3 types of same hidx from quad-mates (VALU DPP)
        float g1 = dpp_mov<0xB1>(g0);         // tau^1
        float g2 = dpp_mov<0x4E>(g0);         // tau^2
        float g3 = dpp_mov<0x1B>(g0);         // tau^3
        bool t0 = (kpos & 1) != 0;            // tau bit0
        bool t1 = (kpos & 2) != 0;            // tau bit1
        float b0 = t0 ? g1 : g0;
        float b1 = t0 ? g0 : g1;
        float b2 = t0 ? g3 : g2;
        float b3 = t0 ? g2 : g3;
        float gi = t1 ? b2 : b0;
        float gf = t1 ? b3 : b1;
        float gg = t1 ? b0 : b2;
        float go = t1 ? b1 : b3;

        c = sigm_fast(gf) * c + sigm_fast(gi) * tanh_fast(gg);
        float h = sigm_fast(go) * tanh_fast(c);
        hmax = fmaxf(hmax, h);

        if ((lane & 3) == 0) h_s[hidx] = h;
        asm volatile("s_waitcnt lgkmcnt(0)\n\ts_barrier" ::: "memory");
        s += ds;
    }

    if ((lane & 3) == 0) pooled[b * 256 + dir * HDIM + hidx] = hmax;
}

// ---------------------------------------------------------------------------
// Kernel 4: classifier (unchanged)
// ---------------------------------------------------------------------------
__global__ void cls_kernel(const float* __restrict__ pooled,
                           const float* __restrict__ W_cls,
                           const float* __restrict__ b_cls,
                           float* __restrict__ out) {
    int i = threadIdx.x;
    if (i < BATCH * 5) {
        int b = i / 5, l = i % 5;
        float acc = b_cls[l];
        const float* p = pooled + b * 256;
        const float* w = W_cls + l * 256;
#pragma unroll 8
        for (int j = 0; j < 256; ++j) acc = fmaf(p[j], w[j], acc);
        out[i] = acc;
    }
}

// ---------------------------------------------------------------------------
extern "C" void kernel_launch(void* const* d_in, const int* in_sizes, int n_in,
                              void* d_out, int out_size, void* d_ws, size_t ws_size,
                              hipStream_t stream) {
    const int*   word_ids   = (const int*)d_in[0];
    const int*   deps_ids   = (const int*)d_in[1];
    const float* word_table = (const float*)d_in[2];
    const float* dep_table  = (const float*)d_in[3];
    const float* Wih_f      = (const float*)d_in[4];
    const float* Whh_f      = (const float*)d_in[5];
    const float* b_f        = (const float*)d_in[6];
    const float* Wih_b      = (const float*)d_in[7];
    const float* Whh_b      = (const float*)d_in[8];
    const float* b_b        = (const float*)d_in[9];
    const float* W_cls      = (const float*)d_in[10];
    const float* b_cls      = (const float*)d_in[11];
    float* out = (float*)d_out;

    // ws layout: pre 67.1 MB | pooled 32 KB | Xcat 31.5 MB | Wcat 2 MB
    float*  pre    = (float*)d_ws;
    float*  pooled = pre + (size_t)BATCH * S_LEN * NCOLS;
    ushort* Xcat   = (ushort*)(pooled + BATCH * 256);
    ushort* Wcat   = Xcat + (size_t)BATCH * S_LEN * K3;

    embed_xcat<<<BATCH * S_LEN, 128, 0, stream>>>(word_ids, deps_ids,
                                                  word_table, dep_table, Xcat);
    wcat_kernel<<<NCOLS, 128, 0, stream>>>(Wih_f, Wih_b, Wcat);
    gemm_mfma<<<dim3(128, 8), 256, 0, stream>>>(Xcat, Wcat, b_f, b_b, pre);
    lstm_rec<<<64, 512, 0, stream>>>(pre, Whh_f, Whh_b, pooled);
    cls_kernel<<<1, 192, 0, stream>>>(pooled, W_cls, b_cls, out);
}

// Round 7
// 597.220 us; speedup vs baseline: 1.7900x; 1.1141x over previous
//
#include <hip/hip_runtime.h>
#include <hip/hip_bf16.h>
#include <cstdint>
#include <cstddef>

#define S_LEN 512
#define BATCH 32
#define EDIM  300
#define KPAD  320
#define K3    960   // [Xh|Xh|Xl] / [Wh|Wl|Wh]
#define HDIM  128
#define NGATE 512   // 4*H
#define NCOLS 1024  // fwd 512 + bwd 512

typedef float    f2  __attribute__((ext_vector_type(2)));
typedef float    f4v __attribute__((ext_vector_type(4)));
typedef short    short8 __attribute__((ext_vector_type(8)));
typedef _Float16 h2  __attribute__((ext_vector_type(2)));

__device__ __forceinline__ float sigm_fast(float x) {
    return __builtin_amdgcn_rcpf(1.f + __expf(-x));
}
__device__ __forceinline__ float tanh_fast(float x) {
    return 2.f * sigm_fast(2.f * x) - 1.f;
}

// DPP cross-lane move (VALU pipe).  quad_perm imm [a,b,c,d] packed in low 8
// bits: 0x00=[0,0,0,0] bcast lane0-of-quad, 0x55=[1,1,1,1], 0xAA=[2,2,2,2],
// 0xFF=[3,3,3,3].
template <int CTRL>
__device__ __forceinline__ float dpp_mov(float x) {
    int r = __builtin_amdgcn_update_dpp(0, __float_as_int(x), CTRL, 0xF, 0xF, true);
    return __int_as_float(r);
}

// pack two f32 -> f16x2 (v_cvt_pkrtz_f16_f32); bit-cast fixes the
// __fp16-vs-_Float16 vector type mismatch (same 32 bits).
__device__ __forceinline__ h2 pk_f16(float a, float b) {
    auto r = __builtin_amdgcn_cvt_pkrtz(a, b);
    return __builtin_bit_cast(h2, r);
}

__device__ __forceinline__ void bf16_split(float v, ushort& hi, ushort& lo) {
    __hip_bfloat16 hb = __float2bfloat16(v);
    float hf = __bfloat162float(hb);
    __hip_bfloat16 lb = __float2bfloat16(v - hf);
    hi = *reinterpret_cast<ushort*>(&hb);
    lo = *reinterpret_cast<ushort*>(&lb);
}

// ---------------------------------------------------------------------------
// Kernel 1: embeddings -> Xcat (bf16 hi/lo split), row = [Xh | Xh | Xl]
// ---------------------------------------------------------------------------
__global__ void embed_xcat(const int* __restrict__ word_ids,
                           const int* __restrict__ deps_ids,
                           const float* __restrict__ word_table,
                           const float* __restrict__ dep_table,
                           ushort* __restrict__ Xcat) {
    int pos = blockIdx.x;
    int b = pos >> 9, s = pos & (S_LEN - 1);
    int wid = word_ids[b * 3 * S_LEN + S_LEN + s];
    const int* dp = deps_ids + (size_t)pos * 8;
    int ids[8];
    int cnt = 0;
#pragma unroll
    for (int d = 0; d < 8; ++d) {
        int id = dp[d];
        ids[d] = id;
        cnt += (id != 0 && id != 1) ? 1 : 0;
    }
    float inv = 0.5f / (float)((cnt > 0) ? cnt : 1);
    const float* wr = word_table + (size_t)wid * EDIM;
    ushort* xr = Xcat + (size_t)pos * K3;
    for (int e = threadIdx.x; e < KPAD; e += 128) {
        float v = 0.f;
        if (e < EDIM) {
            float w = wr[e];
            float dsum = 0.f;
#pragma unroll
            for (int d = 0; d < 8; ++d) {
                if (ids[d] != 0 && ids[d] != 1) dsum += dep_table[ids[d] * EDIM + e];
            }
            v = (cnt > 0) ? (0.5f * w + dsum * inv) : w;
        }
        ushort hu, lu;
        bf16_split(v, hu, lu);
        xr[e] = hu;
        xr[KPAD + e] = hu;
        xr[2 * KPAD + e] = lu;
    }
}

// ---------------------------------------------------------------------------
// Kernel 1b: Wih -> Wcat, row n = [Wh | Wl | Wh]
// ---------------------------------------------------------------------------
__global__ void wcat_kernel(const float* __restrict__ Wih_f,
                            const float* __restrict__ Wih_b,
                            ushort* __restrict__ Wcat) {
    int n = blockIdx.x;
    const float* src = (n < NGATE) ? (Wih_f + (size_t)n * EDIM)
                                   : (Wih_b + (size_t)(n - NGATE) * EDIM);
    ushort* wr = Wcat + (size_t)n * K3;
    for (int e = threadIdx.x; e < KPAD; e += 128) {
        float v = (e < EDIM) ? src[e] : 0.f;
        ushort hu, lu;
        bf16_split(v, hu, lu);
        wr[e] = hu;
        wr[KPAD + e] = lu;
        wr[2 * KPAD + e] = hu;
    }
}

// ---------------------------------------------------------------------------
// Kernel 2: MFMA GEMM (bf16x3).  LDS rows padded 32 -> 40 shorts (80 B) to
// break the 8-way bank conflict on b128 fragment reads.
// ---------------------------------------------------------------------------
#define LSTR 40
__global__ __launch_bounds__(256) void gemm_mfma(
        const ushort* __restrict__ Xcat,
        const ushort* __restrict__ Wcat,
        const float* __restrict__ b_f, const float* __restrict__ b_b,
        float* __restrict__ pre) {
    __shared__ ushort Asub[128 * LSTR];
    __shared__ ushort Bsub[128 * LSTR];
    int tid = threadIdx.x;
    int wave = tid >> 6, lane = tid & 63;
    int lid = lane & 15, quad = lane >> 4;
    int m0 = blockIdx.x * 128, n0 = blockIdx.y * 128;
    int wm = (wave >> 1) * 64, wn = (wave & 1) * 64;

    f4v acc[4][4];
#pragma unroll
    for (int i = 0; i < 4; ++i)
#pragma unroll
        for (int j = 0; j < 4; ++j) acc[i][j] = (f4v)0.f;

    float bias[4];
#pragma unroll
    for (int nt = 0; nt < 4; ++nt) {
        int n = n0 + wn + nt * 16 + lid;
        bias[nt] = (n < NGATE) ? b_f[n] : b_b[n - NGATE];
    }

    int c0 = tid, c1 = tid + 256;
    const ushort* aptr0 = Xcat + (size_t)(m0 + (c0 >> 2)) * K3 + (c0 & 3) * 8;
    const ushort* aptr1 = Xcat + (size_t)(m0 + (c1 >> 2)) * K3 + (c1 & 3) * 8;
    const ushort* bptr0 = Wcat + (size_t)(n0 + (c0 >> 2)) * K3 + (c0 & 3) * 8;
    const ushort* bptr1 = Wcat + (size_t)(n0 + (c1 >> 2)) * K3 + (c1 & 3) * 8;
    int la0 = (c0 >> 2) * LSTR + (c0 & 3) * 8;
    int la1 = (c1 >> 2) * LSTR + (c1 & 3) * 8;

    short8 ra0 = *(const short8*)(aptr0);
    short8 ra1 = *(const short8*)(aptr1);
    short8 rb0 = *(const short8*)(bptr0);
    short8 rb1 = *(const short8*)(bptr1);

    for (int k0 = 0; k0 < K3; k0 += 32) {
        __syncthreads();
        *(short8*)&Asub[la0] = ra0;
        *(short8*)&Asub[la1] = ra1;
        *(short8*)&Bsub[la0] = rb0;
        *(short8*)&Bsub[la1] = rb1;
        __syncthreads();
        if (k0 + 32 < K3) {
            ra0 = *(const short8*)(aptr0 + k0 + 32);
            ra1 = *(const short8*)(aptr1 + k0 + 32);
            rb0 = *(const short8*)(bptr0 + k0 + 32);
            rb1 = *(const short8*)(bptr1 + k0 + 32);
        }
        short8 aF[4], bF[4];
#pragma unroll
        for (int mt = 0; mt < 4; ++mt)
            aF[mt] = *(const short8*)&Asub[(wm + mt * 16 + lid) * LSTR + quad * 8];
#pragma unroll
        for (int nt = 0; nt < 4; ++nt)
            bF[nt] = *(const short8*)&Bsub[(wn + nt * 16 + lid) * LSTR + quad * 8];
#pragma unroll
        for (int mt = 0; mt < 4; ++mt)
#pragma unroll
            for (int nt = 0; nt < 4; ++nt)
                acc[mt][nt] = __builtin_amdgcn_mfma_f32_16x16x32_bf16(
                    aF[mt], bF[nt], acc[mt][nt], 0, 0, 0);
    }

#pragma unroll
    for (int mt = 0; mt < 4; ++mt)
#pragma unroll
        for (int nt = 0; nt < 4; ++nt) {
            int n = n0 + wn + nt * 16 + lid;
#pragma unroll
            for (int r = 0; r < 4; ++r) {
                int m = m0 + wm + mt * 16 + quad * 4 + r;
                pre[(size_t)m * NCOLS + n] = acc[mt][nt][r] + bias[nt];
            }
        }
}

// ---------------------------------------------------------------------------
// Kernel 3: LSTM recurrence v5 — split-N, full-K per lane, no reduction tree.
// 64 blocks (b,dir) x 256 threads (4 waves, 1 block/CU).
// Lane l of wave w: tau = l&3, hx0 = 16w + (l>>2), hx1 = hx0 + 64.
// Owns gate rows tau*128+hx0 and tau*128+hx1 with FULL k=128 dot via
// v_dot2_f32_f16 (f16 weights in 128 VGPRs, fp32 accumulate).
// h lives in LDS as f16 (256 B).  Gate gather: quad_perm broadcasts.
// One lgkm-only barrier/step (global pre-prefetch stays in flight).
// ---------------------------------------------------------------------------
__global__ __launch_bounds__(256, 1) void lstm_rec(
        const float* __restrict__ pre,
        const float* __restrict__ Whh_f, const float* __restrict__ Whh_b,
        float* __restrict__ pooled) {
    __shared__ _Float16 h_s[HDIM];
    int t = threadIdx.x;
    int lane = t & 63;
    int wv = t >> 6;
    int tau = lane & 3;
    int hx0 = wv * 16 + (lane >> 2);
    int hx1 = hx0 + 64;
    int b = blockIdx.x >> 1;
    int dir = blockIdx.x & 1;
    const float* Whh = dir ? Whh_b : Whh_f;

    // f16 weight rows (full k) for the two owned gates: 128 VGPRs
    h2 w0[64], w1[64];
    {
        const float* r0 = Whh + (size_t)(tau * HDIM + hx0) * HDIM;
        const float* r1 = Whh + (size_t)(tau * HDIM + hx1) * HDIM;
#pragma unroll
        for (int q = 0; q < 64; ++q) {
            w0[q] = pk_f16(r0[2 * q], r0[2 * q + 1]);
            w1[q] = pk_f16(r1[2 * q], r1[2 * q + 1]);
        }
    }

    float c0 = 0.f, c1 = 0.f;
    float hmax0 = -1e30f, hmax1 = -1e30f;
    if (t < 64) ((uint*)h_s)[t] = 0u;   // zero 128 f16

    const float* pb0 = pre + (size_t)b * S_LEN * NCOLS + dir * NGATE + tau * HDIM + hx0;
    const float* pb1 = pb0 + 64;
    int s = dir ? (S_LEN - 1) : 0;
    int ds = dir ? -1 : 1;
    float p0n1 = pb0[(long)s * NCOLS];
    float p1n1 = pb1[(long)s * NCOLS];
    float p0n2 = pb0[(long)(s + ds) * NCOLS];
    float p1n2 = pb1[(long)(s + ds) * NCOLS];

    asm volatile("s_waitcnt lgkmcnt(0)\n\ts_barrier" ::: "memory");

    for (int step = 0; step < S_LEN; ++step) {
        float cur0 = p0n1, cur1 = p1n1;
        p0n1 = p0n2; p1n1 = p1n2;
        if (step + 2 < S_LEN) {
            p0n2 = pb0[(long)(s + 2 * ds) * NCOLS];
            p1n2 = pb1[(long)(s + 2 * ds) * NCOLS];
        }

        // read all 128 h (f16) — compiler merges into ds_read_b128s
        h2 hh[64];
        const h2* hp = (const h2*)h_s;
#pragma unroll
        for (int q = 0; q < 64; ++q) hh[q] = hp[q];

        // full-k dots, 4 independent accumulator chains each
        float a0 = 0.f, a1 = 0.f, a2 = 0.f, a3 = 0.f;
        float e0 = 0.f, e1 = 0.f, e2 = 0.f, e3 = 0.f;
#pragma unroll
        for (int q = 0; q < 64; q += 4) {
            a0 = __builtin_amdgcn_fdot2(w0[q + 0], hh[q + 0], a0, false);
            a1 = __builtin_amdgcn_fdot2(w0[q + 1], hh[q + 1], a1, false);
            a2 = __builtin_amdgcn_fdot2(w0[q + 2], hh[q + 2], a2, false);
            a3 = __builtin_amdgcn_fdot2(w0[q + 3], hh[q + 3], a3, false);
            e0 = __builtin_amdgcn_fdot2(w1[q + 0], hh[q + 0], e0, false);
            e1 = __builtin_amdgcn_fdot2(w1[q + 1], hh[q + 1], e1, false);
            e2 = __builtin_amdgcn_fdot2(w1[q + 2], hh[q + 2], e2, false);
            e3 = __builtin_amdgcn_fdot2(w1[q + 3], hh[q + 3], e3, false);
        }
        float g0 = cur0 + (a0 + a1) + (a2 + a3);   // gate (tau, hx0)
        float g1 = cur1 + (e0 + e1) + (e2 + e3);   // gate (tau, hx1)

        // quad broadcasts: pull each tau's gate to all 4 quad lanes
        float gi0 = dpp_mov<0x00>(g0), gf0 = dpp_mov<0x55>(g0);
        float gg0 = dpp_mov<0xAA>(g0), go0 = dpp_mov<0xFF>(g0);
        float gi1 = dpp_mov<0x00>(g1), gf1 = dpp_mov<0x55>(g1);
        float gg1 = dpp_mov<0xAA>(g1), go1 = dpp_mov<0xFF>(g1);

        c0 = sigm_fast(gf0) * c0 + sigm_fast(gi0) * tanh_fast(gg0);
        float h0 = sigm_fast(go0) * tanh_fast(c0);
        c1 = sigm_fast(gf1) * c1 + sigm_fast(gi1) * tanh_fast(gg1);
        float h1 = sigm_fast(go1) * tanh_fast(c1);
        hmax0 = fmaxf(hmax0, h0);
        hmax1 = fmaxf(hmax1, h1);

        if (tau == 0) {
            h_s[hx0] = (_Float16)h0;
            h_s[hx1] = (_Float16)h1;
        }
        asm volatile("s_waitcnt lgkmcnt(0)\n\ts_barrier" ::: "memory");
        s += ds;
    }

    if (tau == 0) {
        pooled[b * 256 + dir * HDIM + hx0] = hmax0;
        pooled[b * 256 + dir * HDIM + hx1] = hmax1;
    }
}

// ---------------------------------------------------------------------------
// Kernel 4: classifier (unchanged)
// ---------------------------------------------------------------------------
__global__ void cls_kernel(const float* __restrict__ pooled,
                           const float* __restrict__ W_cls,
                           const float* __restrict__ b_cls,
                           float* __restrict__ out) {
    int i = threadIdx.x;
    if (i < BATCH * 5) {
        int b = i / 5, l = i % 5;
        float acc = b_cls[l];
        const float* p = pooled + b * 256;
        const float* w = W_cls + l * 256;
#pragma unroll 8
        for (int j = 0; j < 256; ++j) acc = fmaf(p[j], w[j], acc);
        out[i] = acc;
    }
}

// ---------------------------------------------------------------------------
extern "C" void kernel_launch(void* const* d_in, const int* in_sizes, int n_in,
                              void* d_out, int out_size, void* d_ws, size_t ws_size,
                              hipStream_t stream) {
    const int*   word_ids   = (const int*)d_in[0];
    const int*   deps_ids   = (const int*)d_in[1];
    const float* word_table = (const float*)d_in[2];
    const float* dep_table  = (const float*)d_in[3];
    const float* Wih_f      = (const float*)d_in[4];
    const float* Whh_f      = (const float*)d_in[5];
    const float* b_f        = (const float*)d_in[6];
    const float* Wih_b      = (const float*)d_in[7];
    const float* Whh_b      = (const float*)d_in[8];
    const float* b_b        = (const float*)d_in[9];
    const float* W_cls      = (const float*)d_in[10];
    const float* b_cls      = (const float*)d_in[11];
    float* out = (float*)d_out;

    float*  pre    = (float*)d_ws;
    float*  pooled = pre + (size_t)BATCH * S_LEN * NCOLS;
    ushort* Xcat   = (ushort*)(pooled + BATCH * 256);
    ushort* Wcat   = Xcat + (size_t)BATCH * S_LEN * K3;

    embed_xcat<<<BATCH * S_LEN, 128, 0, stream>>>(word_ids, deps_ids,
                                                  word_table, dep_table, Xcat);
    wcat_kernel<<<NCOLS, 128, 0, stream>>>(Wih_f, Wih_b, Wcat);
    gemm_mfma<<<dim3(128, 8), 256, 0, stream>>>(Xcat, Wcat, b_f, b_b, pre);
    lstm_rec<<<64, 256, 0, stream>>>(pre, Whh_f, Whh_b, pooled);
    cls_kernel<<<1, 192, 0, stream>>>(pooled, W_cls, b_cls, out);
}

// Round 8
// 514.529 us; speedup vs baseline: 2.0777x; 1.1607x over previous
//
#include <hip/hip_runtime.h>
#include <hip/hip_bf16.h>
#include <cstdint>
#include <cstddef>

#define S_LEN 512
#define BATCH 32
#define EDIM  300
#define KPAD  320
#define K3    960   // [Xh|Xh|Xl] / [Wh|Wl|Wh]
#define HDIM  128
#define NGATE 512   // 4*H
#define NCOLS 1024  // fwd 512 + bwd 512

typedef float    f2  __attribute__((ext_vector_type(2)));
typedef float    f4v __attribute__((ext_vector_type(4)));
typedef short    short8 __attribute__((ext_vector_type(8)));
typedef _Float16 h2  __attribute__((ext_vector_type(2)));

__device__ __forceinline__ float sigm_fast(float x) {
    return __builtin_amdgcn_rcpf(1.f + __expf(-x));
}
__device__ __forceinline__ float tanh_fast(float x) {
    return 2.f * sigm_fast(2.f * x) - 1.f;
}

// DPP cross-lane move (VALU pipe).
// quad_perm bcasts: 0x00/0x55/0xAA/0xFF = lane 0/1/2/3 of quad to all.
// row rotates: 0x124 = row_ror:4, 0x128 = row_ror:8 (verified R1-R7).
template <int CTRL>
__device__ __forceinline__ float dpp_mov(float x) {
    int r = __builtin_amdgcn_update_dpp(0, __float_as_int(x), CTRL, 0xF, 0xF, true);
    return __int_as_float(r);
}

// pack two f32 -> f16x2 (v_cvt_pkrtz_f16_f32)
__device__ __forceinline__ h2 pk_f16(float a, float b) {
    auto r = __builtin_amdgcn_cvt_pkrtz(a, b);
    return __builtin_bit_cast(h2, r);
}

__device__ __forceinline__ void bf16_split(float v, ushort& hi, ushort& lo) {
    __hip_bfloat16 hb = __float2bfloat16(v);
    float hf = __bfloat162float(hb);
    __hip_bfloat16 lb = __float2bfloat16(v - hf);
    hi = *reinterpret_cast<ushort*>(&hb);
    lo = *reinterpret_cast<ushort*>(&lb);
}

// ---------------------------------------------------------------------------
// Kernel 1: embeddings -> Xcat (bf16 hi/lo split), row = [Xh | Xh | Xl]
// ---------------------------------------------------------------------------
__global__ void embed_xcat(const int* __restrict__ word_ids,
                           const int* __restrict__ deps_ids,
                           const float* __restrict__ word_table,
                           const float* __restrict__ dep_table,
                           ushort* __restrict__ Xcat) {
    int pos = blockIdx.x;
    int b = pos >> 9, s = pos & (S_LEN - 1);
    int wid = word_ids[b * 3 * S_LEN + S_LEN + s];
    const int* dp = deps_ids + (size_t)pos * 8;
    int ids[8];
    int cnt = 0;
#pragma unroll
    for (int d = 0; d < 8; ++d) {
        int id = dp[d];
        ids[d] = id;
        cnt += (id != 0 && id != 1) ? 1 : 0;
    }
    float inv = 0.5f / (float)((cnt > 0) ? cnt : 1);
    const float* wr = word_table + (size_t)wid * EDIM;
    ushort* xr = Xcat + (size_t)pos * K3;
    for (int e = threadIdx.x; e < KPAD; e += 128) {
        float v = 0.f;
        if (e < EDIM) {
            float w = wr[e];
            float dsum = 0.f;
#pragma unroll
            for (int d = 0; d < 8; ++d) {
                if (ids[d] != 0 && ids[d] != 1) dsum += dep_table[ids[d] * EDIM + e];
            }
            v = (cnt > 0) ? (0.5f * w + dsum * inv) : w;
        }
        ushort hu, lu;
        bf16_split(v, hu, lu);
        xr[e] = hu;
        xr[KPAD + e] = hu;
        xr[2 * KPAD + e] = lu;
    }
}

// ---------------------------------------------------------------------------
// Kernel 1b: Wih -> Wcat, row n = [Wh | Wl | Wh]
// ---------------------------------------------------------------------------
__global__ void wcat_kernel(const float* __restrict__ Wih_f,
                            const float* __restrict__ Wih_b,
                            ushort* __restrict__ Wcat) {
    int n = blockIdx.x;
    const float* src = (n < NGATE) ? (Wih_f + (size_t)n * EDIM)
                                   : (Wih_b + (size_t)(n - NGATE) * EDIM);
    ushort* wr = Wcat + (size_t)n * K3;
    for (int e = threadIdx.x; e < KPAD; e += 128) {
        float v = (e < EDIM) ? src[e] : 0.f;
        ushort hu, lu;
        bf16_split(v, hu, lu);
        wr[e] = hu;
        wr[KPAD + e] = lu;
        wr[2 * KPAD + e] = hu;
    }
}

// ---------------------------------------------------------------------------
// Kernel 2: MFMA GEMM (bf16x3), unchanged from R7 (verified).
// ---------------------------------------------------------------------------
#define LSTR 40
__global__ __launch_bounds__(256) void gemm_mfma(
        const ushort* __restrict__ Xcat,
        const ushort* __restrict__ Wcat,
        const float* __restrict__ b_f, const float* __restrict__ b_b,
        float* __restrict__ pre) {
    __shared__ ushort Asub[128 * LSTR];
    __shared__ ushort Bsub[128 * LSTR];
    int tid = threadIdx.x;
    int wave = tid >> 6, lane = tid & 63;
    int lid = lane & 15, quad = lane >> 4;
    int m0 = blockIdx.x * 128, n0 = blockIdx.y * 128;
    int wm = (wave >> 1) * 64, wn = (wave & 1) * 64;

    f4v acc[4][4];
#pragma unroll
    for (int i = 0; i < 4; ++i)
#pragma unroll
        for (int j = 0; j < 4; ++j) acc[i][j] = (f4v)0.f;

    float bias[4];
#pragma unroll
    for (int nt = 0; nt < 4; ++nt) {
        int n = n0 + wn + nt * 16 + lid;
        bias[nt] = (n < NGATE) ? b_f[n] : b_b[n - NGATE];
    }

    int c0 = tid, c1 = tid + 256;
    const ushort* aptr0 = Xcat + (size_t)(m0 + (c0 >> 2)) * K3 + (c0 & 3) * 8;
    const ushort* aptr1 = Xcat + (size_t)(m0 + (c1 >> 2)) * K3 + (c1 & 3) * 8;
    const ushort* bptr0 = Wcat + (size_t)(n0 + (c0 >> 2)) * K3 + (c0 & 3) * 8;
    const ushort* bptr1 = Wcat + (size_t)(n0 + (c1 >> 2)) * K3 + (c1 & 3) * 8;
    int la0 = (c0 >> 2) * LSTR + (c0 & 3) * 8;
    int la1 = (c1 >> 2) * LSTR + (c1 & 3) * 8;

    short8 ra0 = *(const short8*)(aptr0);
    short8 ra1 = *(const short8*)(aptr1);
    short8 rb0 = *(const short8*)(bptr0);
    short8 rb1 = *(const short8*)(bptr1);

    for (int k0 = 0; k0 < K3; k0 += 32) {
        __syncthreads();
        *(short8*)&Asub[la0] = ra0;
        *(short8*)&Asub[la1] = ra1;
        *(short8*)&Bsub[la0] = rb0;
        *(short8*)&Bsub[la1] = rb1;
        __syncthreads();
        if (k0 + 32 < K3) {
            ra0 = *(const short8*)(aptr0 + k0 + 32);
            ra1 = *(const short8*)(aptr1 + k0 + 32);
            rb0 = *(const short8*)(bptr0 + k0 + 32);
            rb1 = *(const short8*)(bptr1 + k0 + 32);
        }
        short8 aF[4], bF[4];
#pragma unroll
        for (int mt = 0; mt < 4; ++mt)
            aF[mt] = *(const short8*)&Asub[(wm + mt * 16 + lid) * LSTR + quad * 8];
#pragma unroll
        for (int nt = 0; nt < 4; ++nt)
            bF[nt] = *(const short8*)&Bsub[(wn + nt * 16 + lid) * LSTR + quad * 8];
#pragma unroll
        for (int mt = 0; mt < 4; ++mt)
#pragma unroll
            for (int nt = 0; nt < 4; ++nt)
                acc[mt][nt] = __builtin_amdgcn_mfma_f32_16x16x32_bf16(
                    aF[mt], bF[nt], acc[mt][nt], 0, 0, 0);
    }

#pragma unroll
    for (int mt = 0; mt < 4; ++mt)
#pragma unroll
        for (int nt = 0; nt < 4; ++nt) {
            int n = n0 + wn + nt * 16 + lid;
#pragma unroll
            for (int r = 0; r < 4; ++r) {
                int m = m0 + wm + mt * 16 + quad * 4 + r;
                pre[(size_t)m * NCOLS + n] = acc[mt][nt][r] + bias[nt];
            }
        }
}

// ---------------------------------------------------------------------------
// Kernel 3: LSTM recurrence v6 — split-k-4, 4x less LDS pipe.
// 64 blocks (b,dir) x 256 threads.  Lane l: tau=l&3 (gate type),
// ks=(l>>2)&3 (k-slice [32ks,32ks+32)), hi2=l>>4.
// Lane computes partials for 8 gate rows j=0..7:
//   row = tau*128 + hidx(j),  hidx(j) = 32*wv + 8*hi2 + j.
// k-combine across the 4 ks copies (lanes 4 apart in 16-row) via the
// verified ror:4+ror:8 rotate-reduce.  Quad gathers gate types for the
// two owned hidx (j=2ks, 2ks+1); lanes tau<2 activate X, tau>=2 activate Y.
// One lgkm-only barrier/step; global pre prefetch stays in flight.
// ---------------------------------------------------------------------------
__global__ __launch_bounds__(256, 1) void lstm_rec(
        const float* __restrict__ pre,
        const float* __restrict__ Whh_f, const float* __restrict__ Whh_b,
        float* __restrict__ pooled) {
    __shared__ _Float16 h_s[HDIM];
    int t = threadIdx.x;
    int lane = t & 63;
    int wv = t >> 6;
    int tau = lane & 3;
    int ks  = (lane >> 2) & 3;
    int hi2 = lane >> 4;
    int hbase = wv * 32 + hi2 * 8;          // hidx(j) = hbase + j
    int b = blockIdx.x >> 1;
    int dir = blockIdx.x & 1;
    const float* Whh = dir ? Whh_b : Whh_f;

    // f16 weights: w[j][q] = Whh[tau*128 + hbase+j][32ks + 2q, +1]  (128 VGPRs)
    h2 w[8][16];
#pragma unroll
    for (int j = 0; j < 8; ++j) {
        const float* rp = Whh + (size_t)(tau * HDIM + hbase + j) * HDIM + ks * 32;
#pragma unroll
        for (int q = 0; q < 16; ++q) w[j][q] = pk_f16(rp[2 * q], rp[2 * q + 1]);
    }

    float c = 0.f;
    float hmax = -1e30f;
    if (t < 64) ((uint*)h_s)[t] = 0u;       // zero 128 f16

    // owned pre columns: gates (tau, hbase+2ks) and (tau, hbase+2ks+1)
    const float* pX = pre + (size_t)b * S_LEN * NCOLS + dir * NGATE
                    + tau * HDIM + hbase + 2 * ks;
    const float* pY = pX + 1;
    int s = dir ? (S_LEN - 1) : 0;
    int sd = dir ? -1 : 1;
    float pXn1 = pX[(long)s * NCOLS], pYn1 = pY[(long)s * NCOLS];
    float pXn2 = pX[(long)(s + sd) * NCOLS], pYn2 = pY[(long)(s + sd) * NCOLS];

    int hZ = hbase + 2 * ks + (tau >> 1);   // hidx this lane's activation owns

    asm volatile("s_waitcnt lgkmcnt(0)\n\ts_barrier" ::: "memory");

    for (int step = 0; step < S_LEN; ++step) {
        float curX = pXn1, curY = pYn1;
        pXn1 = pXn2; pYn1 = pYn2;
        if (step + 2 < S_LEN) {
            pXn2 = pX[(long)(s + 2 * sd) * NCOLS];
            pYn2 = pY[(long)(s + 2 * sd) * NCOLS];
        }

        // h slice for this lane's k-range: 16 h2 = 64 B = 4 x ds_read_b128
        h2 hh[16];
        const h2* hp = (const h2*)h_s;
#pragma unroll
        for (int q = 0; q < 16; ++q) hh[q] = hp[ks * 16 + q];

        // 8 partial dots over the owned k-slice (8 independent chains)
        float P[8];
#pragma unroll
        for (int j = 0; j < 8; ++j) {
            float acc = 0.f;
#pragma unroll
            for (int q = 0; q < 16; ++q)
                acc = __builtin_amdgcn_fdot2(w[j][q], hh[q], acc, false);
            P[j] = acc;
        }

        // k-combine across the 4 ks lanes (4 apart): verified rotate-reduce
        float R[8];
#pragma unroll
        for (int j = 0; j < 8; ++j) {
            float r = P[j];
            r += dpp_mov<0x124>(r);   // row_ror:4
            r += dpp_mov<0x128>(r);   // row_ror:8
            R[j] = r;                 // full dot for gate (tau, hbase+j)
        }

        // select this lane's two owned gates (j = 2ks, 2ks+1)
        float X01 = (ks & 1) ? R[2] : R[0];
        float X23 = (ks & 1) ? R[6] : R[4];
        float X   = (ks & 2) ? X23 : X01;
        float Y01 = (ks & 1) ? R[3] : R[1];
        float Y23 = (ks & 1) ? R[7] : R[5];
        float Y   = (ks & 2) ? Y23 : Y01;
        float gX = X + curX;          // gate (tau, hbase+2ks)
        float gY = Y + curY;          // gate (tau, hbase+2ks+1)

        // quad broadcasts: all 4 gate types of both owned hidx
        float giX = dpp_mov<0x00>(gX), gfX = dpp_mov<0x55>(gX);
        float ggX = dpp_mov<0xAA>(gX), goX = dpp_mov<0xFF>(gX);
        float giY = dpp_mov<0x00>(gY), gfY = dpp_mov<0x55>(gY);
        float ggY = dpp_mov<0xAA>(gY), goY = dpp_mov<0xFF>(gY);

        // lanes tau<2 activate X (hidx hbase+2ks), tau>=2 activate Y (+1)
        bool oy = (tau & 2) != 0;
        float gi = oy ? giY : giX;
        float gf = oy ? gfY : gfX;
        float gg = oy ? ggY : ggX;
        float go = oy ? goY : goX;

        c = sigm_fast(gf) * c + sigm_fast(gi) * tanh_fast(gg);
        float h = sigm_fast(go) * tanh_fast(c);
        hmax = fmaxf(hmax, h);

        if ((tau & 1) == 0) h_s[hZ] = (_Float16)h;   // tau 0 & 2 write
        asm volatile("s_waitcnt lgkmcnt(0)\n\ts_barrier" ::: "memory");
        s += sd;
    }

    if ((tau & 1) == 0) pooled[b * 256 + dir * HDIM + hZ] = hmax;
}

// ---------------------------------------------------------------------------
// Kernel 4: classifier (unchanged)
// ---------------------------------------------------------------------------
__global__ void cls_kernel(const float* __restrict__ pooled,
                           const float* __restrict__ W_cls,
                           const float* __restrict__ b_cls,
                           float* __restrict__ out) {
    int i = threadIdx.x;
    if (i < BATCH * 5) {
        int b = i / 5, l = i % 5;
        float acc = b_cls[l];
        const float* p = pooled + b * 256;
        const float* w = W_cls + l * 256;
#pragma unroll 8
        for (int j = 0; j < 256; ++j) acc = fmaf(p[j], w[j], acc);
        out[i] = acc;
    }
}

// ---------------------------------------------------------------------------
extern "C" void kernel_launch(void* const* d_in, const int* in_sizes, int n_in,
                              void* d_out, int out_size, void* d_ws, size_t ws_size,
                              hipStream_t stream) {
    const int*   word_ids   = (const int*)d_in[0];
    const int*   deps_ids   = (const int*)d_in[1];
    const float* word_table = (const float*)d_in[2];
    const float* dep_table  = (const float*)d_in[3];
    const float* Wih_f      = (const float*)d_in[4];
    const float* Whh_f      = (const float*)d_in[5];
    const float* b_f        = (const float*)d_in[6];
    const float* Wih_b      = (const float*)d_in[7];
    const float* Whh_b      = (const float*)d_in[8];
    const float* b_b        = (const float*)d_in[9];
    const float* W_cls      = (const float*)d_in[10];
    const float* b_cls      = (const float*)d_in[11];
    float* out = (float*)d_out;

    float*  pre    = (float*)d_ws;
    float*  pooled = pre + (size_t)BATCH * S_LEN * NCOLS;
    ushort* Xcat   = (ushort*)(pooled + BATCH * 256);
    ushort* Wcat   = Xcat + (size_t)BATCH * S_LEN * K3;

    embed_xcat<<<BATCH * S_LEN, 128, 0, stream>>>(word_ids, deps_ids,
                                                  word_table, dep_table, Xcat);
    wcat_kernel<<<NCOLS, 128, 0, stream>>>(Wih_f, Wih_b, Wcat);
    gemm_mfma<<<dim3(128, 8), 256, 0, stream>>>(Xcat, Wcat, b_f, b_b, pre);
    lstm_rec<<<64, 256, 0, stream>>>(pre, Whh_f, Whh_b, pooled);
    cls_kernel<<<1, 192, 0, stream>>>(pooled, W_cls, b_cls, out);
}